// Round 3
// baseline (5633.569 us; speedup 1.0000x reference)
//
#include <hip/hip_runtime.h>
#include <math.h>

#define LOG2_CONST 0.6931471805599453f

__device__ __forceinline__ float sspf(float x) {
    // softplus(x) - log(2), numerically stable
    float sp = (x > 0.0f) ? (x + log1pf(expf(-x))) : log1pf(expf(x));
    return sp - LOG2_CONST;
}

// -------------------- Kernel A: h = x @ lin1_w.T --------------------
__global__ __launch_bounds__(256) void lin1_kernel(const float* __restrict__ x,
        const float* __restrict__ w, float* __restrict__ h, int N) {
    __shared__ float wT[128 * 128];
    __shared__ float xs[32 * 128];
    int tid = threadIdx.x;
    for (int idx = tid; idx < 128 * 128; idx += 256) {
        int f = idx >> 7, k = idx & 127;
        wT[k * 128 + f] = w[idx];
    }
    int nbase = blockIdx.x * 32;
    for (int idx = tid; idx < 32 * 128; idx += 256) {
        int n = nbase + (idx >> 7);
        xs[idx] = (n < N) ? x[(size_t)n * 128 + (idx & 127)] : 0.0f;
    }
    __syncthreads();
    int wave = tid >> 6, lane = tid & 63;
    int f2 = lane * 2;
    float acc0[8], acc1[8];
#pragma unroll
    for (int j = 0; j < 8; ++j) { acc0[j] = 0.0f; acc1[j] = 0.0f; }
    for (int k = 0; k < 128; k += 4) {
        float2 wv0 = *(const float2*)&wT[(k + 0) * 128 + f2];
        float2 wv1 = *(const float2*)&wT[(k + 1) * 128 + f2];
        float2 wv2 = *(const float2*)&wT[(k + 2) * 128 + f2];
        float2 wv3 = *(const float2*)&wT[(k + 3) * 128 + f2];
#pragma unroll
        for (int j = 0; j < 8; ++j) {
            float4 xv = *(const float4*)&xs[(wave * 8 + j) * 128 + k];
            acc0[j] += xv.x * wv0.x; acc1[j] += xv.x * wv0.y;
            acc0[j] += xv.y * wv1.x; acc1[j] += xv.y * wv1.y;
            acc0[j] += xv.z * wv2.x; acc1[j] += xv.z * wv2.y;
            acc0[j] += xv.w * wv3.x; acc1[j] += xv.w * wv3.y;
        }
    }
#pragma unroll
    for (int j = 0; j < 8; ++j) {
        int n = nbase + wave * 8 + j;
        if (n < N) {
            float2 o = {acc0[j], acc1[j]};
            *(float2*)&h[(size_t)n * 128 + f2] = o;
        }
    }
}

// -------------------- Kernel B: fused edge MLP + gather + scatter ----------
// block = 256 (4 waves), 32 edges per block-iteration (8 per wave).
// Lane owns features (2f,2f+1). Inner loops vectorized: per 4-k block,
// 4x ds_read_b64 (weights, 2-way=free) + 8x ds_read_b128 broadcasts (edges)
// feed 64 FMAs -> VALU-bound. LDS ~121KB -> 1 block/CU.
__global__ __launch_bounds__(256) void edge_kernel(
    const float* __restrict__ edge_attr, const float* __restrict__ edge_weight,
    const int* __restrict__ edge_index,
    const float* __restrict__ mw1, const float* __restrict__ mb1,
    const float* __restrict__ mw2, const float* __restrict__ mb2,
    const float* __restrict__ h, float* __restrict__ agg,
    int E, int G, int iters)
{
    __shared__ float w1t[64 * 128];    // [k][f], rows >= G zeroed
    __shared__ float w2t[128 * 128];   // [k][f]
    __shared__ float ea_lds[32 * 64];  // [edge][k], stride 64, zero-padded
    __shared__ float t_lds[32 * 128];  // [edge][f]
    __shared__ int   sIdx[32];
    __shared__ int   dIdx[32];
    __shared__ float cVal[32];

    int tid = threadIdx.x;
    // stage weights (transposed); zero w1t pad rows so 0*garbage can't NaN
    for (int idx = tid; idx < 64 * 128; idx += 256) w1t[idx] = 0.0f;
    __syncthreads();
    for (int idx = tid; idx < 128 * G; idx += 256) {
        int f = idx / G, k = idx - f * G;   // mw1 is [128][G] row-major
        w1t[k * 128 + f] = mw1[idx];
    }
    for (int idx = tid; idx < 128 * 128; idx += 256) {
        int f = idx >> 7, k = idx & 127;
        w2t[k * 128 + f] = mw2[idx];
    }
    int wave = tid >> 6, lane = tid & 63;
    int f2 = lane * 2;
    float rb1x = mb1[f2], rb1y = mb1[f2 + 1];
    float rb2x = mb2[f2], rb2y = mb2[f2 + 1];
    int kmax1 = (G + 3) & ~3;   // 52 for G=50

    for (int it = 0; it < iters; ++it) {
        long long ebase = ((long long)blockIdx.x + (long long)it * gridDim.x) * 32;
        __syncthreads();  // protect staging LDS reused from previous iteration
        // stage 32 edge_attr rows into stride-64 layout (zero-padded cols)
        for (int idx = tid; idx < 32 * 64; idx += 256) {
            int row = idx >> 6, col = idx & 63;
            long long e = ebase + row;
            float v = 0.0f;
            if (col < G && e < E) v = edge_attr[e * G + col];
            ea_lds[idx] = v;
        }
        if (tid < 32) {
            long long e = ebase + tid;
            if (e < E) {
                sIdx[tid] = edge_index[e];
                dIdx[tid] = edge_index[(long long)E + e];
                float w = edge_weight[e];
                cVal[tid] = 10.0f / (1e-10f + w * w) - 1.0f;
            } else { sIdx[tid] = 0; dIdx[tid] = 0; cVal[tid] = 0.0f; }
        }
        __syncthreads();

        // ---- layer 1: t = ssp(ea @ W1^T + b1) ----
        float a0[8], a1[8];
#pragma unroll
        for (int j = 0; j < 8; ++j) { a0[j] = rb1x; a1[j] = rb1y; }
        for (int k = 0; k < kmax1; k += 4) {
            float2 wv0 = *(const float2*)&w1t[(k + 0) * 128 + f2];
            float2 wv1 = *(const float2*)&w1t[(k + 1) * 128 + f2];
            float2 wv2 = *(const float2*)&w1t[(k + 2) * 128 + f2];
            float2 wv3 = *(const float2*)&w1t[(k + 3) * 128 + f2];
#pragma unroll
            for (int j = 0; j < 8; ++j) {
                float4 ev = *(const float4*)&ea_lds[(wave * 8 + j) * 64 + k];
                a0[j] += ev.x * wv0.x; a1[j] += ev.x * wv0.y;
                a0[j] += ev.y * wv1.x; a1[j] += ev.y * wv1.y;
                a0[j] += ev.z * wv2.x; a1[j] += ev.z * wv2.y;
                a0[j] += ev.w * wv3.x; a1[j] += ev.w * wv3.y;
            }
        }
#pragma unroll
        for (int j = 0; j < 8; ++j) {
            float2 tv = { sspf(a0[j]), sspf(a1[j]) };
            *(float2*)&t_lds[(wave * 8 + j) * 128 + f2] = tv;
        }
        __syncthreads();  // order t_lds writes before reads

        // ---- layer 2: W = (t @ W2^T + b2) * C ----
        float c0[8], c1[8];
#pragma unroll
        for (int j = 0; j < 8; ++j) { c0[j] = rb2x; c1[j] = rb2y; }
        for (int k = 0; k < 128; k += 4) {
            float2 wv0 = *(const float2*)&w2t[(k + 0) * 128 + f2];
            float2 wv1 = *(const float2*)&w2t[(k + 1) * 128 + f2];
            float2 wv2 = *(const float2*)&w2t[(k + 2) * 128 + f2];
            float2 wv3 = *(const float2*)&w2t[(k + 3) * 128 + f2];
#pragma unroll
            for (int j = 0; j < 8; ++j) {
                float4 tv = *(const float4*)&t_lds[(wave * 8 + j) * 128 + k];
                c0[j] += tv.x * wv0.x; c1[j] += tv.x * wv0.y;
                c0[j] += tv.y * wv1.x; c1[j] += tv.y * wv1.y;
                c0[j] += tv.z * wv2.x; c1[j] += tv.z * wv2.y;
                c0[j] += tv.w * wv3.x; c1[j] += tv.w * wv3.y;
            }
        }

        // ---- gather h[src], scale, scatter-add at dst ----
#pragma unroll
        for (int j = 0; j < 8; ++j) {
            long long e = ebase + wave * 8 + j;
            if (e < E) {
                int el = wave * 8 + j;
                int s = sIdx[el], d = dIdx[el];
                float Cv = cVal[el];
                float2 hv = *(const float2*)&h[(size_t)s * 128 + f2];
                atomicAdd(&agg[(size_t)d * 128 + f2],     hv.x * c0[j] * Cv);
                atomicAdd(&agg[(size_t)d * 128 + f2 + 1], hv.y * c1[j] * Cv);
            }
        }
    }
}

// -------------------- Kernel C: per-component sums + counts ---------------
__global__ void comp_scatter(const float* __restrict__ agg,
                             const int* __restrict__ member,
                             const int* __restrict__ seg,
                             float* __restrict__ sums, int T) {
    long long gid = (long long)blockIdx.x * blockDim.x + threadIdx.x;
    long long total = (long long)T * 64;
    if (gid >= total) return;
    int t = (int)(gid >> 6);
    int p = (int)(gid & 63) * 2;
    int row = member[t];
    int c = seg[t];
    float2 v = *(const float2*)&agg[(size_t)row * 128 + p];
    atomicAdd(&sums[(size_t)c * 128 + p],     v.x);
    atomicAdd(&sums[(size_t)c * 128 + p + 1], v.y);
}

__global__ void cnt_kernel(const int* __restrict__ seg, float* __restrict__ cnt, int T) {
    int t = blockIdx.x * blockDim.x + threadIdx.x;
    if (t < T) atomicAdd(&cnt[seg[t]], 1.0f);
}

// -------------------- Kernel D: mean -> lin2 -> ssp -> lin ----------------
__global__ __launch_bounds__(128) void head_kernel(
    const float* __restrict__ sums, const float* __restrict__ cnt,
    const float* __restrict__ l2w, const float* __restrict__ l2b,
    const float* __restrict__ lw, const float* __restrict__ lb,
    float* __restrict__ out) {
    __shared__ float l2t[128 * 128];
    __shared__ float lwt[128 * 128];
    __shared__ float mean_s[128];
    __shared__ float s_s[128];
    int tid = threadIdx.x;
    for (int idx = tid; idx < 128 * 128; idx += 128) {
        int f = idx >> 7, k = idx & 127;
        l2t[k * 128 + f] = l2w[idx];
        lwt[k * 128 + f] = lw[idx];
    }
    int c = blockIdx.x;
    float cn = fmaxf(cnt[c], 1.0f);
    mean_s[tid] = sums[(size_t)c * 128 + tid] / cn;
    __syncthreads();
    float acc = l2b[tid];
    for (int k = 0; k < 128; ++k) acc += mean_s[k] * l2t[k * 128 + tid];
    s_s[tid] = sspf(acc);
    __syncthreads();
    float acc2 = lb[tid];
    for (int k = 0; k < 128; ++k) acc2 += s_s[k] * lwt[k * 128 + tid];
    out[(size_t)c * 128 + tid] = acc2;
}

extern "C" void kernel_launch(void* const* d_in, const int* in_sizes, int n_in,
                              void* d_out, int out_size, void* d_ws, size_t ws_size,
                              hipStream_t stream) {
    const float* x           = (const float*)d_in[0];
    const int*   edge_index  = (const int*)d_in[1];
    const float* edge_weight = (const float*)d_in[2];
    const float* edge_attr   = (const float*)d_in[3];
    const int*   comp_member = (const int*)d_in[4];
    const int*   comp_seg    = (const int*)d_in[5];
    const float* mw1 = (const float*)d_in[6];
    const float* mb1 = (const float*)d_in[7];
    const float* mw2 = (const float*)d_in[8];
    const float* mb2 = (const float*)d_in[9];
    const float* l1w = (const float*)d_in[10];
    const float* l2w = (const float*)d_in[11];
    const float* l2b = (const float*)d_in[12];
    const float* lw  = (const float*)d_in[13];
    const float* lb  = (const float*)d_in[14];
    float* out = (float*)d_out;

    int N  = in_sizes[0] / 128;
    int E  = in_sizes[2];
    int G  = in_sizes[3] / E;      // 50
    int NC = out_size / 128;       // 2000
    int T  = in_sizes[4];          // comp_member length (== N)

    float* h    = (float*)d_ws;
    float* agg  = h + (size_t)N * 128;
    float* sums = agg + (size_t)N * 128;
    float* cnt  = sums + (size_t)NC * 128;

    // zero agg + sums + cnt (contiguous)
    size_t zeroBytes = ((size_t)N * 128 + (size_t)NC * 128 + (size_t)NC) * sizeof(float);
    hipMemsetAsync(agg, 0, zeroBytes, stream);

    lin1_kernel<<<(N + 31) / 32, 256, 0, stream>>>(x, l1w, h, N);

    int grid = 1024;
    long long per = (long long)grid * 32;
    int iters = (int)((E + per - 1) / per);
    edge_kernel<<<grid, 256, 0, stream>>>(edge_attr, edge_weight, edge_index,
                                          mw1, mb1, mw2, mb2, h, agg, E, G, iters);

    long long ct = (long long)T * 64;
    comp_scatter<<<(int)((ct + 255) / 256), 256, 0, stream>>>(agg, comp_member, comp_seg, sums, T);
    cnt_kernel<<<(T + 255) / 256, 256, 0, stream>>>(comp_seg, cnt, T);
    head_kernel<<<NC, 128, 0, stream>>>(sums, cnt, l2w, l2b, lw, lb, out);
}

// Round 4
// 2516.873 us; speedup vs baseline: 2.2383x; 2.2383x over previous
//
#include <hip/hip_runtime.h>
#include <math.h>

#define LOG2_CONST 0.6931471805599453f

typedef __attribute__((ext_vector_type(8))) short bf16x8;
typedef __attribute__((ext_vector_type(4))) float f32x4;

__device__ __forceinline__ float sspf(float x) {
    // softplus(x) - log(2), numerically stable
    float sp = (x > 0.0f) ? (x + log1pf(expf(-x))) : log1pf(expf(x));
    return sp - LOG2_CONST;
}

__device__ __forceinline__ short f2bf(float f) {
    // f32 -> bf16 round-to-nearest-even
    union { float f; unsigned u; } v; v.f = f;
    unsigned r = v.u + 0x7FFFu + ((v.u >> 16) & 1u);
    return (short)(r >> 16);
}

// -------------------- Kernel A: h = x @ lin1_w.T (f32, exact) -------------
__global__ __launch_bounds__(256) void lin1_kernel(const float* __restrict__ x,
        const float* __restrict__ w, float* __restrict__ h, int N) {
    __shared__ float wT[128 * 128];
    __shared__ float xs[32 * 128];
    int tid = threadIdx.x;
    for (int idx = tid; idx < 128 * 128; idx += 256) {
        int f = idx >> 7, k = idx & 127;
        wT[k * 128 + f] = w[idx];
    }
    int nbase = blockIdx.x * 32;
    for (int idx = tid; idx < 32 * 128; idx += 256) {
        int n = nbase + (idx >> 7);
        xs[idx] = (n < N) ? x[(size_t)n * 128 + (idx & 127)] : 0.0f;
    }
    __syncthreads();
    int wave = tid >> 6, lane = tid & 63;
    int f2 = lane * 2;
    float acc0[8], acc1[8];
#pragma unroll
    for (int j = 0; j < 8; ++j) { acc0[j] = 0.0f; acc1[j] = 0.0f; }
    for (int k = 0; k < 128; k += 4) {
        float2 wv0 = *(const float2*)&wT[(k + 0) * 128 + f2];
        float2 wv1 = *(const float2*)&wT[(k + 1) * 128 + f2];
        float2 wv2 = *(const float2*)&wT[(k + 2) * 128 + f2];
        float2 wv3 = *(const float2*)&wT[(k + 3) * 128 + f2];
#pragma unroll
        for (int j = 0; j < 8; ++j) {
            float4 xv = *(const float4*)&xs[(wave * 8 + j) * 128 + k];
            acc0[j] += xv.x * wv0.x; acc1[j] += xv.x * wv0.y;
            acc0[j] += xv.y * wv1.x; acc1[j] += xv.y * wv1.y;
            acc0[j] += xv.z * wv2.x; acc1[j] += xv.z * wv2.y;
            acc0[j] += xv.w * wv3.x; acc1[j] += xv.w * wv3.y;
        }
    }
#pragma unroll
    for (int j = 0; j < 8; ++j) {
        int n = nbase + wave * 8 + j;
        if (n < N) {
            float2 o = {acc0[j], acc1[j]};
            *(float2*)&h[(size_t)n * 128 + f2] = o;
        }
    }
}

// -------------------- Kernel B: MFMA edge MLP + gather + direct scatter ----
// 256 threads = 4 waves; tile = 32 edges x 128 features. Wave w owns cols
// [w*32, w*32+32). Layer1: A(ea->bf16) from global, B1 from LDS frag-order,
// K=64 (padded from G). Layer2: t through LDS [32][136] bf16, B2 frag-order.
// Epilogue: msg = h[src][col] * (acc2+b2) * C, atomicAdd direct into
// sums[comp_seg[dst]] (1MB, cache-resident -> no HBM write-through storm).
// MFMA frag layout (16x16x32 bf16): A: lane l holds A[l&15][(l>>4)*8 + j];
// B: lane l holds B[(l>>4)*8 + j][l&15]; C/D: col=lane&15, row=(lane>>4)*4+reg
// (m89-verified C/D).
__global__ __launch_bounds__(256) void edge_mfma_kernel(
    const float* __restrict__ edge_attr, const float* __restrict__ edge_weight,
    const int* __restrict__ edge_index, const int* __restrict__ comp_seg,
    const float* __restrict__ mw1, const float* __restrict__ mb1,
    const float* __restrict__ mw2, const float* __restrict__ mb2,
    const float* __restrict__ h, float* __restrict__ sums,
    int E, int G, int ntiles)
{
    __shared__ __align__(16) short B1s[64 * 128];   // [(ks*4+kc)*128+col][j8]
    __shared__ __align__(16) short B2s[128 * 128];  // [(ks*4+kc)*128+col][j8]
    __shared__ __align__(16) short Ts[32 * 136];    // [row][col] stride 136
    __shared__ int   sIdx[2][32];
    __shared__ int   dSeg[2][32];
    __shared__ float cVal[2][32];

    int tid = threadIdx.x;
    // Stage W1^T, W2^T in B-fragment order (once per block; bf16).
    for (int idx = tid; idx < 64 * 128; idx += 256) {
        int col = idx >> 6, k = idx & 63;
        float v = (k < G) ? mw1[col * G + k] : 0.0f;   // mw1 [128][G]
        int ks = k >> 5, kc = (k >> 3) & 3, j = k & 7;
        B1s[(((ks * 4 + kc) * 128 + col) << 3) + j] = f2bf(v);
    }
    for (int idx = tid; idx < 128 * 128; idx += 256) {
        int col = idx >> 7, k = idx & 127;
        int ks = k >> 5, kc = (k >> 3) & 3, j = k & 7;
        B2s[(((ks * 4 + kc) * 128 + col) << 3) + j] = f2bf(mw2[col * 128 + k]);
    }
    int wave = tid >> 6, lane = tid & 63;
    int r16 = lane & 15, kg = lane >> 4;   // kg = k-chunk / lane-group
    int wcol = wave * 32;
    float rb1[2], rb2[2];
    rb1[0] = mb1[wcol + r16];      rb1[1] = mb1[wcol + 16 + r16];
    rb2[0] = mb2[wcol + r16];      rb2[1] = mb2[wcol + 16 + r16];

    int it = 0;
    for (long long tile = blockIdx.x; tile < ntiles; tile += gridDim.x, ++it) {
        int pb = it & 1;
        long long ebase = tile * 32;
        if (tid < 32) {
            long long e = ebase + tid;
            if (e < (long long)E) {
                int d = edge_index[(long long)E + e];
                sIdx[pb][tid] = edge_index[e];
                dSeg[pb][tid] = comp_seg[d];
                float w = edge_weight[e];
                cVal[pb][tid] = 10.0f / (1e-10f + w * w) - 1.0f;
            } else { sIdx[pb][tid] = 0; dSeg[pb][tid] = 0; cVal[pb][tid] = 0.0f; }
        }
        __syncthreads();  // staged scalars visible; prev-tile Ts reads complete

        // ---- layer 1: acc1 = ea @ W1^T  (A from global, K padded to 64) ----
        f32x4 acc1[2][2] = {};
        bf16x8 a1[2][2];
#pragma unroll
        for (int mi = 0; mi < 2; ++mi)
#pragma unroll
        for (int ks = 0; ks < 2; ++ks) {
            long long e = ebase + mi * 16 + r16;
            if (e >= (long long)E) e = (long long)E - 1;  // masked via cVal=0
            int kbase = ks * 32 + kg * 8;
            const float* ap = edge_attr + e * (long long)G + kbase;
            bf16x8 a;
            if (kbase + 8 <= G) {
                float2 p0 = ((const float2*)ap)[0];
                float2 p1 = ((const float2*)ap)[1];
                float2 p2 = ((const float2*)ap)[2];
                float2 p3 = ((const float2*)ap)[3];
                a[0] = f2bf(p0.x); a[1] = f2bf(p0.y);
                a[2] = f2bf(p1.x); a[3] = f2bf(p1.y);
                a[4] = f2bf(p2.x); a[5] = f2bf(p2.y);
                a[6] = f2bf(p3.x); a[7] = f2bf(p3.y);
            } else {
#pragma unroll
                for (int j = 0; j < 8; ++j)
                    a[j] = (kbase + j < G) ? f2bf(ap[j]) : (short)0;
            }
            a1[mi][ks] = a;
        }
#pragma unroll
        for (int ks = 0; ks < 2; ++ks)
#pragma unroll
        for (int ni = 0; ni < 2; ++ni) {
            bf16x8 b = *(const bf16x8*)&B1s[(((ks * 4 + kg) * 128 + wcol + ni * 16 + r16) << 3)];
#pragma unroll
            for (int mi = 0; mi < 2; ++mi)
                acc1[mi][ni] = __builtin_amdgcn_mfma_f32_16x16x32_bf16(
                                   a1[mi][ks], b, acc1[mi][ni], 0, 0, 0);
        }
        // ssp + write t (bf16) into Ts
#pragma unroll
        for (int mi = 0; mi < 2; ++mi)
#pragma unroll
        for (int ni = 0; ni < 2; ++ni)
#pragma unroll
        for (int reg = 0; reg < 4; ++reg) {
            float tv = sspf(acc1[mi][ni][reg] + rb1[ni]);
            int row = mi * 16 + kg * 4 + reg;
            int col = wcol + ni * 16 + r16;
            Ts[row * 136 + col] = f2bf(tv);
        }
        __syncthreads();  // Ts complete

        // ---- layer 2: acc2 = t @ W2^T ----
        f32x4 acc2[2][2] = {};
#pragma unroll
        for (int ks = 0; ks < 4; ++ks) {
            bf16x8 a2[2];
#pragma unroll
            for (int mi = 0; mi < 2; ++mi)
                a2[mi] = *(const bf16x8*)&Ts[(mi * 16 + r16) * 136 + ks * 32 + kg * 8];
#pragma unroll
            for (int ni = 0; ni < 2; ++ni) {
                bf16x8 b = *(const bf16x8*)&B2s[(((ks * 4 + kg) * 128 + wcol + ni * 16 + r16) << 3)];
#pragma unroll
                for (int mi = 0; mi < 2; ++mi)
                    acc2[mi][ni] = __builtin_amdgcn_mfma_f32_16x16x32_bf16(
                                       a2[mi], b, acc2[mi][ni], 0, 0, 0);
            }
        }

        // ---- epilogue: msg = h[src]*W*C, atomic into sums[seg[dst]] ----
#pragma unroll
        for (int mi = 0; mi < 2; ++mi)
#pragma unroll
        for (int ni = 0; ni < 2; ++ni) {
            int col = wcol + ni * 16 + r16;
#pragma unroll
            for (int reg = 0; reg < 4; ++reg) {
                int erow = mi * 16 + kg * 4 + reg;
                float Cv = cVal[pb][erow];
                float Wv = (acc2[mi][ni][reg] + rb2[ni]) * Cv;
                float hv = h[(size_t)sIdx[pb][erow] * 128 + col];
                atomicAdd(&sums[(size_t)dSeg[pb][erow] * 128 + col], hv * Wv);
            }
        }
    }
}

// -------------------- Kernel C: per-component counts ----------------------
__global__ void cnt_kernel(const int* __restrict__ seg, float* __restrict__ cnt, int T) {
    int t = blockIdx.x * blockDim.x + threadIdx.x;
    if (t < T) atomicAdd(&cnt[seg[t]], 1.0f);
}

// -------------------- Kernel D: mean -> lin2 -> ssp -> lin ----------------
__global__ __launch_bounds__(128) void head_kernel(
    const float* __restrict__ sums, const float* __restrict__ cnt,
    const float* __restrict__ l2w, const float* __restrict__ l2b,
    const float* __restrict__ lw, const float* __restrict__ lb,
    float* __restrict__ out) {
    __shared__ float l2t[128 * 128];
    __shared__ float lwt[128 * 128];
    __shared__ float mean_s[128];
    __shared__ float s_s[128];
    int tid = threadIdx.x;
    for (int idx = tid; idx < 128 * 128; idx += 128) {
        int f = idx >> 7, k = idx & 127;
        l2t[k * 128 + f] = l2w[idx];
        lwt[k * 128 + f] = lw[idx];
    }
    int c = blockIdx.x;
    float cn = fmaxf(cnt[c], 1.0f);
    mean_s[tid] = sums[(size_t)c * 128 + tid] / cn;
    __syncthreads();
    float acc = l2b[tid];
    for (int k = 0; k < 128; ++k) acc += mean_s[k] * l2t[k * 128 + tid];
    s_s[tid] = sspf(acc);
    __syncthreads();
    float acc2 = lb[tid];
    for (int k = 0; k < 128; ++k) acc2 += s_s[k] * lwt[k * 128 + tid];
    out[(size_t)c * 128 + tid] = acc2;
}

extern "C" void kernel_launch(void* const* d_in, const int* in_sizes, int n_in,
                              void* d_out, int out_size, void* d_ws, size_t ws_size,
                              hipStream_t stream) {
    const float* x           = (const float*)d_in[0];
    const int*   edge_index  = (const int*)d_in[1];
    const float* edge_weight = (const float*)d_in[2];
    const float* edge_attr   = (const float*)d_in[3];
    const int*   comp_seg    = (const int*)d_in[5];
    const float* mw1 = (const float*)d_in[6];
    const float* mb1 = (const float*)d_in[7];
    const float* mw2 = (const float*)d_in[8];
    const float* mb2 = (const float*)d_in[9];
    const float* l1w = (const float*)d_in[10];
    const float* l2w = (const float*)d_in[11];
    const float* l2b = (const float*)d_in[12];
    const float* lw  = (const float*)d_in[13];
    const float* lb  = (const float*)d_in[14];
    float* out = (float*)d_out;

    int N  = in_sizes[0] / 128;
    int E  = in_sizes[2];
    int G  = in_sizes[3] / E;      // 50
    int NC = out_size / 128;       // 2000
    int T  = in_sizes[4];          // comp_member length (== N)

    float* h    = (float*)d_ws;
    float* sums = h + (size_t)N * 128;
    float* cnt  = sums + (size_t)NC * 128;

    // zero sums + cnt (contiguous, ~1 MB)
    size_t zeroBytes = ((size_t)NC * 128 + (size_t)NC) * sizeof(float);
    hipMemsetAsync(sums, 0, zeroBytes, stream);

    lin1_kernel<<<(N + 31) / 32, 256, 0, stream>>>(x, l1w, h, N);

    int ntiles = (E + 31) / 32;
    edge_mfma_kernel<<<512, 256, 0, stream>>>(edge_attr, edge_weight, edge_index,
                                              comp_seg, mw1, mb1, mw2, mb2,
                                              h, sums, E, G, ntiles);

    cnt_kernel<<<(T + 255) / 256, 256, 0, stream>>>(comp_seg, cnt, T);
    head_kernel<<<NC, 128, 0, stream>>>(sums, cnt, l2w, l2b, lw, lb, out);
}